// Round 9
// baseline (130.208 us; speedup 1.0000x reference)
//
#include <hip/hip_runtime.h>
#include <hip/hip_bf16.h>
#include <stdint.h>

#define NODES 50000
#define EDGES 800000
#define CAP   64        // per-node bucket capacity (deg ~ Poisson(16), max<64 verified by pass)

typedef __attribute__((ext_vector_type(8))) short bf16x8;
typedef __attribute__((ext_vector_type(8))) unsigned short u16x8;
typedef __attribute__((ext_vector_type(4))) unsigned short u16x4;
typedef __attribute__((ext_vector_type(4))) float f32x4;
typedef unsigned short ushort_t;

__device__ __forceinline__ ushort_t f2bf(float f) {   // RNE f32->bf16 bits
    unsigned u = __float_as_uint(f);
    unsigned r = (u + 0x7fff + ((u >> 16) & 1)) >> 16;
    return (ushort_t)r;
}
__device__ __forceinline__ float bf2f(ushort_t h) {
    return __uint_as_float(((unsigned)h) << 16);
}

// ---------------- merged prep ----------------
// blocks [0,3128):      XCD-partitioned bucket fill (group g = b&7 owns nodes
//                       [g*6250,(g+1)*6250) -> esrc/deg lines stay in one L2)
// blocks [3128,9378):   x -> bf16 into xbf (NT load + NT store: don't evict
//                       the fill's esrc/deg/edge lines)
// blocks [9378,9394):   pack w1 into MFMA fragment order
// blocks [9394,9399):   pack w2 likewise
__global__ __launch_bounds__(256) void prep(
    const float* __restrict__ x, const int* __restrict__ src,
    const int* __restrict__ dst,
    const float* __restrict__ Wr1, const float* __restrict__ Wl1,
    const float* __restrict__ Wr2, const float* __restrict__ Wl2,
    int* __restrict__ deg, ushort_t* __restrict__ esrc,
    ushort_t* __restrict__ xbf, ushort_t* __restrict__ w1p,
    ushort_t* __restrict__ w2p) {
    int b = blockIdx.x;
    if (b < 3128) {                       // 391 chunks x 8 groups
        int g = b & 7, chunk = b >> 3;
        int lo = g * 6250;
#pragma unroll
        for (int k = 0; k < 8; ++k) {
            int e = chunk * 2048 + k * 256 + threadIdx.x;
            if (e < EDGES) {
                int d = dst[e];
                if ((unsigned)(d - lo) < 6250u) {
                    int s = src[e];
                    int p = atomicAdd(&deg[d], 1);
                    if (p < CAP) esrc[(size_t)d * CAP + p] = (ushort_t)s;
                }
            }
        }
    } else if (b < 9378) {                // 6250*256 == NODES*32 exactly
        int idx = (b - 3128) * 256 + threadIdx.x;
        int i = idx >> 5, c = idx & 31;
        f32x4 v = __builtin_nontemporal_load(
            reinterpret_cast<const f32x4*>(x + (size_t)i * 128 + c * 4));
        u16x4 h;
        h[0] = f2bf(v[0]); h[1] = f2bf(v[1]); h[2] = f2bf(v[2]); h[3] = f2bf(v[3]);
        __builtin_nontemporal_store(h,
            reinterpret_cast<u16x4*>(xbf + (size_t)i * 128 + c * 4));
    } else if (b < 9394) {                // 4096 threads: w1 fragment pack
        int t = (b - 9378) * 256 + threadIdx.x;     // t = (nf*8+kc)*64+lane
        int nf = t >> 9, kc = (t >> 6) & 7, lane = t & 63;
        int r = nf * 16 + (lane & 15);
        int k2 = kc * 32 + ((lane >> 4) << 3);
        u16x8 o;
#pragma unroll
        for (int j = 0; j < 8; ++j) {
            int kk = k2 + j;
            float v = (kk < 128) ? Wr1[r * 128 + kk] : Wl1[r * 128 + (kk - 128)];
            o[j] = f2bf(v);
        }
        *reinterpret_cast<u16x8*>(w1p + (size_t)t * 8) = o;
    } else {                              // 1280 threads: w2 fragment pack
        int t = (b - 9394) * 256 + threadIdx.x;     // t = (nf*4+kc)*64+lane
        if (t >= 1280) return;
        int nf = t >> 8, kc = (t >> 6) & 3, lane = t & 63;
        int r = nf * 16 + (lane & 15);
        int k2 = kc * 32 + ((lane >> 4) << 3);
        u16x8 o;
#pragma unroll
        for (int j = 0; j < 8; ++j) {
            int kk = k2 + j;
            float v = (r < 40) ? Wr2[r * 128 + kk] : Wl2[(r - 40) * 128 + kk];
            o[j] = f2bf(v);
        }
        *reinterpret_cast<u16x8*>(w2p + (size_t)t * 8) = o;
    }
}

// ---------------- layer-1 gather-mean (bf16), MLP-unrolled ----------------
// 16 lanes/node, ushort8 (16B) per lane; 4 neighbors in flight, 2 acc chains.
// Gathers from dense xbf (12.8 MB, fully-used lines); writes mbf via NT.
__global__ __launch_bounds__(256) void aggx(
    const ushort_t* __restrict__ xbf, ushort_t* __restrict__ mbf,
    const ushort_t* __restrict__ esrc, const int* __restrict__ deg) {
    int idx = blockIdx.x * 256 + threadIdx.x;
    int i = idx >> 4, c = idx & 15;
    if (i >= NODES) return;
    int dg = deg[i];
    int n = dg < CAP ? dg : CAP;
    const ushort_t* ep = esrc + (size_t)i * CAP;
    float a0[8] = {}, a1[8] = {};
    int j = 0;
    for (; j + 4 <= n; j += 4) {
        int s0 = ep[j], s1 = ep[j + 1], s2 = ep[j + 2], s3 = ep[j + 3];
        u16x8 v0 = *reinterpret_cast<const u16x8*>(xbf + (size_t)s0 * 128 + c * 8);
        u16x8 v1 = *reinterpret_cast<const u16x8*>(xbf + (size_t)s1 * 128 + c * 8);
        u16x8 v2 = *reinterpret_cast<const u16x8*>(xbf + (size_t)s2 * 128 + c * 8);
        u16x8 v3 = *reinterpret_cast<const u16x8*>(xbf + (size_t)s3 * 128 + c * 8);
#pragma unroll
        for (int k = 0; k < 8; ++k) {
            a0[k] += bf2f(v0[k]) + bf2f(v2[k]);
            a1[k] += bf2f(v1[k]) + bf2f(v3[k]);
        }
    }
    for (; j < n; ++j) {
        int s = ep[j];
        u16x8 v = *reinterpret_cast<const u16x8*>(xbf + (size_t)s * 128 + c * 8);
#pragma unroll
        for (int k = 0; k < 8; ++k) a0[k] += bf2f(v[k]);
    }
    float ci = 1.0f / fmaxf((float)dg, 1.0f);
    u16x8 m;
#pragma unroll
    for (int k = 0; k < 8; ++k) m[k] = f2bf((a0[k] + a1[k]) * ci);
    __builtin_nontemporal_store(m,
        reinterpret_cast<u16x8*>(mbf + (size_t)i * 128 + c * 8));
}

// ---------------- fused GEMM1 + GEMM2 (packed weights, split A) ----------------
// Phase 1: emb[64 rows x 128] = [xbf|mbf] @ W1^T + b1; relu->bf16 LDS tile
//          emb -> f32 out (NT: never re-read on device)
// Phase 2: V[rows x 80] = h_lds[rows,128] @ W2^T -> bf16 (cached: agg2 re-reads)
__global__ __launch_bounds__(256) void gemm12(
    const ushort_t* __restrict__ xbf, const ushort_t* __restrict__ mbf,
    const ushort_t* __restrict__ w1p, const ushort_t* __restrict__ w2p,
    const float* __restrict__ b1, float* __restrict__ emb,
    ushort_t* __restrict__ V, int M) {
    __shared__ ushort_t hs[64][136];      // stride 136: 16B-aligned rows
    const int wave = threadIdx.x >> 6, lane = threadIdx.x & 63;
    const int r0 = blockIdx.x * 64 + wave * 16;
    int arow = r0 + (lane & 15); if (arow >= M) arow = M - 1;
    const int klane = (lane >> 4) * 8;

    f32x4 acc[8] = {};
#pragma unroll
    for (int kc = 0; kc < 8; ++kc) {
        const ushort_t* abase = (kc < 4) ? xbf : mbf;
        bf16x8 a = *reinterpret_cast<const bf16x8*>(
            abase + (size_t)arow * 128 + (kc & 3) * 32 + klane);
        bf16x8 wv[8];
#pragma unroll
        for (int nf = 0; nf < 8; ++nf)
            wv[nf] = *reinterpret_cast<const bf16x8*>(
                w1p + (size_t)((nf * 8 + kc) * 64 + lane) * 8);
#pragma unroll
        for (int nf = 0; nf < 8; ++nf)
            acc[nf] = __builtin_amdgcn_mfma_f32_16x16x32_bf16(a, wv[nf], acc[nf], 0, 0, 0);
    }

    const int crow0r = wave * 16 + (lane >> 4) * 4;     // row within tile
    const int crow0  = blockIdx.x * 64 + crow0r;
    const int ccol   = lane & 15;
#pragma unroll
    for (int nf = 0; nf < 8; ++nf) {
        int col = nf * 16 + ccol;
        float bv = b1[col];
#pragma unroll
        for (int r = 0; r < 4; ++r) {
            int row = crow0 + r;
            float val = acc[nf][r] + bv;
            if (row < M)
                __builtin_nontemporal_store(val, emb + (size_t)row * 128 + col);
            hs[crow0r + r][col] = f2bf(fmaxf(val, 0.f));
        }
    }
    __syncthreads();

    f32x4 acc2[5] = {};
#pragma unroll
    for (int kc = 0; kc < 4; ++kc) {
        bf16x8 a = *reinterpret_cast<const bf16x8*>(
            &hs[wave * 16 + (lane & 15)][kc * 32 + klane]);
        bf16x8 wv[5];
#pragma unroll
        for (int nf = 0; nf < 5; ++nf)
            wv[nf] = *reinterpret_cast<const bf16x8*>(
                w2p + (size_t)((nf * 4 + kc) * 64 + lane) * 8);
#pragma unroll
        for (int nf = 0; nf < 5; ++nf)
            acc2[nf] = __builtin_amdgcn_mfma_f32_16x16x32_bf16(a, wv[nf], acc2[nf], 0, 0, 0);
    }
#pragma unroll
    for (int nf = 0; nf < 5; ++nf) {
        int col = nf * 16 + ccol;
#pragma unroll
        for (int r = 0; r < 4; ++r) {
            int row = crow0 + r;
            if (row < M) V[(size_t)row * 80 + col] = f2bf(acc2[nf][r]);
        }
    }
}

// ---------------- layer-2 gather-mean + epilogue (bf16 V), MLP-unrolled ----------------
// 8 lanes/node, lanes 0..4 carry ushort8 (40 cols); logits = self + mean + b2.
__global__ __launch_bounds__(256) void agg2(
    const ushort_t* __restrict__ V, const ushort_t* __restrict__ esrc,
    const int* __restrict__ deg, const float* __restrict__ b2,
    float* __restrict__ logits) {
    int idx = blockIdx.x * 256 + threadIdx.x;
    int i = idx >> 3, c = idx & 7;
    if (i >= NODES || c >= 5) return;
    int dg = deg[i];
    int n = dg < CAP ? dg : CAP;
    const ushort_t* ep = esrc + (size_t)i * CAP;
    float a0[8] = {}, a1[8] = {};
    int j = 0;
    for (; j + 4 <= n; j += 4) {
        int s0 = ep[j], s1 = ep[j + 1], s2 = ep[j + 2], s3 = ep[j + 3];
        u16x8 v0 = *reinterpret_cast<const u16x8*>(V + (size_t)s0 * 80 + 40 + c * 8);
        u16x8 v1 = *reinterpret_cast<const u16x8*>(V + (size_t)s1 * 80 + 40 + c * 8);
        u16x8 v2 = *reinterpret_cast<const u16x8*>(V + (size_t)s2 * 80 + 40 + c * 8);
        u16x8 v3 = *reinterpret_cast<const u16x8*>(V + (size_t)s3 * 80 + 40 + c * 8);
#pragma unroll
        for (int k = 0; k < 8; ++k) {
            a0[k] += bf2f(v0[k]) + bf2f(v2[k]);
            a1[k] += bf2f(v1[k]) + bf2f(v3[k]);
        }
    }
    for (; j < n; ++j) {
        int s = ep[j];
        u16x8 v = *reinterpret_cast<const u16x8*>(V + (size_t)s * 80 + 40 + c * 8);
#pragma unroll
        for (int k = 0; k < 8; ++k) a0[k] += bf2f(v[k]);
    }
    float ci = 1.0f / fmaxf((float)dg, 1.0f);
    u16x8 sv = *reinterpret_cast<const u16x8*>(V + (size_t)i * 80 + c * 8);
    float o[8];
#pragma unroll
    for (int k = 0; k < 8; ++k)
        o[k] = bf2f(sv[k]) + (a0[k] + a1[k]) * ci + b2[c * 8 + k];
    float4* dst4 = reinterpret_cast<float4*>(logits + (size_t)i * 40 + c * 8);
    dst4[0] = make_float4(o[0], o[1], o[2], o[3]);
    dst4[1] = make_float4(o[4], o[5], o[6], o[7]);
}

extern "C" void kernel_launch(void* const* d_in, const int* in_sizes, int n_in,
                              void* d_out, int out_size, void* d_ws, size_t ws_size,
                              hipStream_t stream) {
    const float* x   = (const float*)d_in[0];
    const int*   ei  = (const int*)d_in[1];
    const float* Wl1 = (const float*)d_in[2];
    const float* Wr1 = (const float*)d_in[3];
    const float* b1  = (const float*)d_in[4];
    const float* Wl2 = (const float*)d_in[5];
    const float* Wr2 = (const float*)d_in[6];
    const float* b2  = (const float*)d_in[7];
    const int* src = ei;              // edge_index[0]
    const int* dst = ei + EDGES;      // edge_index[1]

    // Workspace (~40.3 MB):
    //   [0, 12.8M)       xbf [50000x128 bf16]
    //   [12.8M, 25.6M)   mbf [50000x128 bf16]
    //   [25.6M, 33.6M)   V   [50000x80 bf16]
    //   [33.6M, 40.0M)   esrc [50000*64 ushort]
    //   [40.0M, 40.2M)   deg [50000 int]
    //   [40.2M, ...)     w1p [32768 bf16 packed], w2p [10240 bf16 packed]
    char* ws = (char*)d_ws;
    ushort_t* xbf  = (ushort_t*)ws;
    ushort_t* mbf  = (ushort_t*)(ws + 12800000);
    ushort_t* V    = (ushort_t*)(ws + 25600000);
    ushort_t* esrc = (ushort_t*)(ws + 33600000);
    int*      deg  = (int*)(ws + 40000000);
    ushort_t* w1p  = (ushort_t*)(ws + 40200000);
    ushort_t* w2p  = (ushort_t*)(ws + 40265536);

    float* logits_out = (float*)d_out;                   // 50000*40 f32
    float* emb_out    = logits_out + (size_t)NODES * 40; // 50000*128 f32

    hipMemsetAsync(deg, 0, (size_t)NODES * 4, stream);

    prep<<<9399, 256, 0, stream>>>(x, src, dst, Wr1, Wl1, Wr2, Wl2,
                                   deg, esrc, xbf, w1p, w2p);

    aggx<<<3125, 256, 0, stream>>>(xbf, mbf, esrc, deg);

    gemm12<<<(NODES + 63) / 64, 256, 0, stream>>>(xbf, mbf, w1p, w2p, b1,
                                                  emb_out, V, NODES);

    agg2<<<(NODES * 8 + 255) / 256, 256, 0, stream>>>(V, esrc, deg, b2, logits_out);
}

// Round 10
// 126.160 us; speedup vs baseline: 1.0321x; 1.0321x over previous
//
#include <hip/hip_runtime.h>
#include <hip/hip_bf16.h>
#include <stdint.h>

#define NODES 50000
#define EDGES 800000
#define CAP   64        // per-node bucket capacity (deg ~ Poisson(16), max<64 verified by pass)

typedef __attribute__((ext_vector_type(8))) short bf16x8;
typedef __attribute__((ext_vector_type(8))) unsigned short u16x8;
typedef __attribute__((ext_vector_type(4))) unsigned short u16x4;
typedef __attribute__((ext_vector_type(4))) float f32x4;
typedef unsigned short ushort_t;

__device__ __forceinline__ ushort_t f2bf(float f) {   // RNE f32->bf16 bits
    unsigned u = __float_as_uint(f);
    unsigned r = (u + 0x7fff + ((u >> 16) & 1)) >> 16;
    return (ushort_t)r;
}
__device__ __forceinline__ float bf2f(ushort_t h) {
    return __uint_as_float(((unsigned)h) << 16);
}

// ---------------- merged prep ----------------
// blocks [0,3128):      XCD-partitioned bucket fill. Group g = b&7 owns nodes
//                       [g*6250,(g+1)*6250). dst/src loads are NON-TEMPORAL:
//                       the streaming edge data must NOT evict the group's
//                       esrc/deg lines from its XCD L2 (they are re-touched
//                       ~16x per line; eviction mid-fill = repeated write-back).
// blocks [3128,9378):   x -> bf16 into xbf. NT load of x (streamed once);
//                       NORMAL store of xbf (aggx gathers it heavily -> keep in L2).
// blocks [9378,9394):   pack w1 into MFMA fragment order
// blocks [9394,9399):   pack w2 likewise
__global__ __launch_bounds__(256) void prep(
    const float* __restrict__ x, const int* __restrict__ src,
    const int* __restrict__ dst,
    const float* __restrict__ Wr1, const float* __restrict__ Wl1,
    const float* __restrict__ Wr2, const float* __restrict__ Wl2,
    int* __restrict__ deg, ushort_t* __restrict__ esrc,
    ushort_t* __restrict__ xbf, ushort_t* __restrict__ w1p,
    ushort_t* __restrict__ w2p) {
    int b = blockIdx.x;
    if (b < 3128) {                       // 391 chunks x 8 groups
        int g = b & 7, chunk = b >> 3;
        int lo = g * 6250;
#pragma unroll
        for (int k = 0; k < 8; ++k) {
            int e = chunk * 2048 + k * 256 + threadIdx.x;
            if (e < EDGES) {
                int d = __builtin_nontemporal_load(dst + e);
                if ((unsigned)(d - lo) < 6250u) {
                    int s = __builtin_nontemporal_load(src + e);
                    int p = atomicAdd(&deg[d], 1);
                    if (p < CAP) esrc[(size_t)d * CAP + p] = (ushort_t)s;
                }
            }
        }
    } else if (b < 9378) {                // 6250*256 == NODES*32 exactly
        int idx = (b - 3128) * 256 + threadIdx.x;
        int i = idx >> 5, c = idx & 31;
        f32x4 v = __builtin_nontemporal_load(
            reinterpret_cast<const f32x4*>(x + (size_t)i * 128 + c * 4));
        u16x4 h;
        h[0] = f2bf(v[0]); h[1] = f2bf(v[1]); h[2] = f2bf(v[2]); h[3] = f2bf(v[3]);
        *reinterpret_cast<u16x4*>(xbf + (size_t)i * 128 + c * 4) = h;
    } else if (b < 9394) {                // 4096 threads: w1 fragment pack
        int t = (b - 9378) * 256 + threadIdx.x;     // t = (nf*8+kc)*64+lane
        int nf = t >> 9, kc = (t >> 6) & 7, lane = t & 63;
        int r = nf * 16 + (lane & 15);
        int k2 = kc * 32 + ((lane >> 4) << 3);
        u16x8 o;
#pragma unroll
        for (int j = 0; j < 8; ++j) {
            int kk = k2 + j;
            float v = (kk < 128) ? Wr1[r * 128 + kk] : Wl1[r * 128 + (kk - 128)];
            o[j] = f2bf(v);
        }
        *reinterpret_cast<u16x8*>(w1p + (size_t)t * 8) = o;
    } else {                              // 1280 threads: w2 fragment pack
        int t = (b - 9394) * 256 + threadIdx.x;     // t = (nf*4+kc)*64+lane
        if (t >= 1280) return;
        int nf = t >> 8, kc = (t >> 6) & 3, lane = t & 63;
        int r = nf * 16 + (lane & 15);
        int k2 = kc * 32 + ((lane >> 4) << 3);
        u16x8 o;
#pragma unroll
        for (int j = 0; j < 8; ++j) {
            int kk = k2 + j;
            float v = (r < 40) ? Wr2[r * 128 + kk] : Wl2[(r - 40) * 128 + kk];
            o[j] = f2bf(v);
        }
        *reinterpret_cast<u16x8*>(w2p + (size_t)t * 8) = o;
    }
}

// ---------------- layer-1 gather-mean (bf16), MLP-unrolled ----------------
// 16 lanes/node, ushort8 (16B) per lane; 4 neighbors in flight, 2 acc chains.
// Gathers from dense xbf; mbf stored NORMALLY (gemm12 re-reads it).
__global__ __launch_bounds__(256) void aggx(
    const ushort_t* __restrict__ xbf, ushort_t* __restrict__ mbf,
    const ushort_t* __restrict__ esrc, const int* __restrict__ deg) {
    int idx = blockIdx.x * 256 + threadIdx.x;
    int i = idx >> 4, c = idx & 15;
    if (i >= NODES) return;
    int dg = deg[i];
    int n = dg < CAP ? dg : CAP;
    const ushort_t* ep = esrc + (size_t)i * CAP;
    float a0[8] = {}, a1[8] = {};
    int j = 0;
    for (; j + 4 <= n; j += 4) {
        int s0 = ep[j], s1 = ep[j + 1], s2 = ep[j + 2], s3 = ep[j + 3];
        u16x8 v0 = *reinterpret_cast<const u16x8*>(xbf + (size_t)s0 * 128 + c * 8);
        u16x8 v1 = *reinterpret_cast<const u16x8*>(xbf + (size_t)s1 * 128 + c * 8);
        u16x8 v2 = *reinterpret_cast<const u16x8*>(xbf + (size_t)s2 * 128 + c * 8);
        u16x8 v3 = *reinterpret_cast<const u16x8*>(xbf + (size_t)s3 * 128 + c * 8);
#pragma unroll
        for (int k = 0; k < 8; ++k) {
            a0[k] += bf2f(v0[k]) + bf2f(v2[k]);
            a1[k] += bf2f(v1[k]) + bf2f(v3[k]);
        }
    }
    for (; j < n; ++j) {
        int s = ep[j];
        u16x8 v = *reinterpret_cast<const u16x8*>(xbf + (size_t)s * 128 + c * 8);
#pragma unroll
        for (int k = 0; k < 8; ++k) a0[k] += bf2f(v[k]);
    }
    float ci = 1.0f / fmaxf((float)dg, 1.0f);
    u16x8 m;
#pragma unroll
    for (int k = 0; k < 8; ++k) m[k] = f2bf((a0[k] + a1[k]) * ci);
    *reinterpret_cast<u16x8*>(mbf + (size_t)i * 128 + c * 8) = m;
}

// ---------------- fused GEMM1 + GEMM2 (packed weights, split A) ----------------
// Phase 1: emb[64 rows x 128] = [xbf|mbf] @ W1^T + b1; relu->bf16 LDS tile
//          emb -> f32 out (NT: never re-read on device)
// Phase 2: V[rows x 80] = h_lds[rows,128] @ W2^T -> bf16 (cached: agg2 re-reads)
__global__ __launch_bounds__(256) void gemm12(
    const ushort_t* __restrict__ xbf, const ushort_t* __restrict__ mbf,
    const ushort_t* __restrict__ w1p, const ushort_t* __restrict__ w2p,
    const float* __restrict__ b1, float* __restrict__ emb,
    ushort_t* __restrict__ V, int M) {
    __shared__ ushort_t hs[64][136];      // stride 136: 16B-aligned rows
    const int wave = threadIdx.x >> 6, lane = threadIdx.x & 63;
    const int r0 = blockIdx.x * 64 + wave * 16;
    int arow = r0 + (lane & 15); if (arow >= M) arow = M - 1;
    const int klane = (lane >> 4) * 8;

    f32x4 acc[8] = {};
#pragma unroll
    for (int kc = 0; kc < 8; ++kc) {
        const ushort_t* abase = (kc < 4) ? xbf : mbf;
        bf16x8 a = *reinterpret_cast<const bf16x8*>(
            abase + (size_t)arow * 128 + (kc & 3) * 32 + klane);
        bf16x8 wv[8];
#pragma unroll
        for (int nf = 0; nf < 8; ++nf)
            wv[nf] = *reinterpret_cast<const bf16x8*>(
                w1p + (size_t)((nf * 8 + kc) * 64 + lane) * 8);
#pragma unroll
        for (int nf = 0; nf < 8; ++nf)
            acc[nf] = __builtin_amdgcn_mfma_f32_16x16x32_bf16(a, wv[nf], acc[nf], 0, 0, 0);
    }

    const int crow0r = wave * 16 + (lane >> 4) * 4;     // row within tile
    const int crow0  = blockIdx.x * 64 + crow0r;
    const int ccol   = lane & 15;
#pragma unroll
    for (int nf = 0; nf < 8; ++nf) {
        int col = nf * 16 + ccol;
        float bv = b1[col];
#pragma unroll
        for (int r = 0; r < 4; ++r) {
            int row = crow0 + r;
            float val = acc[nf][r] + bv;
            if (row < M)
                __builtin_nontemporal_store(val, emb + (size_t)row * 128 + col);
            hs[crow0r + r][col] = f2bf(fmaxf(val, 0.f));
        }
    }
    __syncthreads();

    f32x4 acc2[5] = {};
#pragma unroll
    for (int kc = 0; kc < 4; ++kc) {
        bf16x8 a = *reinterpret_cast<const bf16x8*>(
            &hs[wave * 16 + (lane & 15)][kc * 32 + klane]);
        bf16x8 wv[5];
#pragma unroll
        for (int nf = 0; nf < 5; ++nf)
            wv[nf] = *reinterpret_cast<const bf16x8*>(
                w2p + (size_t)((nf * 4 + kc) * 64 + lane) * 8);
#pragma unroll
        for (int nf = 0; nf < 5; ++nf)
            acc2[nf] = __builtin_amdgcn_mfma_f32_16x16x32_bf16(a, wv[nf], acc2[nf], 0, 0, 0);
    }
#pragma unroll
    for (int nf = 0; nf < 5; ++nf) {
        int col = nf * 16 + ccol;
#pragma unroll
        for (int r = 0; r < 4; ++r) {
            int row = crow0 + r;
            if (row < M) V[(size_t)row * 80 + col] = f2bf(acc2[nf][r]);
        }
    }
}

// ---------------- layer-2 gather-mean + epilogue (bf16 V), MLP-unrolled ----------------
// 8 lanes/node, lanes 0..4 carry ushort8 (40 cols); logits = self + mean + b2.
__global__ __launch_bounds__(256) void agg2(
    const ushort_t* __restrict__ V, const ushort_t* __restrict__ esrc,
    const int* __restrict__ deg, const float* __restrict__ b2,
    float* __restrict__ logits) {
    int idx = blockIdx.x * 256 + threadIdx.x;
    int i = idx >> 3, c = idx & 7;
    if (i >= NODES || c >= 5) return;
    int dg = deg[i];
    int n = dg < CAP ? dg : CAP;
    const ushort_t* ep = esrc + (size_t)i * CAP;
    float a0[8] = {}, a1[8] = {};
    int j = 0;
    for (; j + 4 <= n; j += 4) {
        int s0 = ep[j], s1 = ep[j + 1], s2 = ep[j + 2], s3 = ep[j + 3];
        u16x8 v0 = *reinterpret_cast<const u16x8*>(V + (size_t)s0 * 80 + 40 + c * 8);
        u16x8 v1 = *reinterpret_cast<const u16x8*>(V + (size_t)s1 * 80 + 40 + c * 8);
        u16x8 v2 = *reinterpret_cast<const u16x8*>(V + (size_t)s2 * 80 + 40 + c * 8);
        u16x8 v3 = *reinterpret_cast<const u16x8*>(V + (size_t)s3 * 80 + 40 + c * 8);
#pragma unroll
        for (int k = 0; k < 8; ++k) {
            a0[k] += bf2f(v0[k]) + bf2f(v2[k]);
            a1[k] += bf2f(v1[k]) + bf2f(v3[k]);
        }
    }
    for (; j < n; ++j) {
        int s = ep[j];
        u16x8 v = *reinterpret_cast<const u16x8*>(V + (size_t)s * 80 + 40 + c * 8);
#pragma unroll
        for (int k = 0; k < 8; ++k) a0[k] += bf2f(v[k]);
    }
    float ci = 1.0f / fmaxf((float)dg, 1.0f);
    u16x8 sv = *reinterpret_cast<const u16x8*>(V + (size_t)i * 80 + c * 8);
    float o[8];
#pragma unroll
    for (int k = 0; k < 8; ++k)
        o[k] = bf2f(sv[k]) + (a0[k] + a1[k]) * ci + b2[c * 8 + k];
    float4* dst4 = reinterpret_cast<float4*>(logits + (size_t)i * 40 + c * 8);
    dst4[0] = make_float4(o[0], o[1], o[2], o[3]);
    dst4[1] = make_float4(o[4], o[5], o[6], o[7]);
}

extern "C" void kernel_launch(void* const* d_in, const int* in_sizes, int n_in,
                              void* d_out, int out_size, void* d_ws, size_t ws_size,
                              hipStream_t stream) {
    const float* x   = (const float*)d_in[0];
    const int*   ei  = (const int*)d_in[1];
    const float* Wl1 = (const float*)d_in[2];
    const float* Wr1 = (const float*)d_in[3];
    const float* b1  = (const float*)d_in[4];
    const float* Wl2 = (const float*)d_in[5];
    const float* Wr2 = (const float*)d_in[6];
    const float* b2  = (const float*)d_in[7];
    const int* src = ei;              // edge_index[0]
    const int* dst = ei + EDGES;      // edge_index[1]

    // Workspace (~40.3 MB):
    //   [0, 12.8M)       xbf [50000x128 bf16]
    //   [12.8M, 25.6M)   mbf [50000x128 bf16]
    //   [25.6M, 33.6M)   V   [50000x80 bf16]
    //   [33.6M, 40.0M)   esrc [50000*64 ushort]
    //   [40.0M, 40.2M)   deg [50000 int]
    //   [40.2M, ...)     w1p [32768 bf16 packed], w2p [10240 bf16 packed]
    char* ws = (char*)d_ws;
    ushort_t* xbf  = (ushort_t*)ws;
    ushort_t* mbf  = (ushort_t*)(ws + 12800000);
    ushort_t* V    = (ushort_t*)(ws + 25600000);
    ushort_t* esrc = (ushort_t*)(ws + 33600000);
    int*      deg  = (int*)(ws + 40000000);
    ushort_t* w1p  = (ushort_t*)(ws + 40200000);
    ushort_t* w2p  = (ushort_t*)(ws + 40265536);

    float* logits_out = (float*)d_out;                   // 50000*40 f32
    float* emb_out    = logits_out + (size_t)NODES * 40; // 50000*128 f32

    hipMemsetAsync(deg, 0, (size_t)NODES * 4, stream);

    prep<<<9399, 256, 0, stream>>>(x, src, dst, Wr1, Wl1, Wr2, Wl2,
                                   deg, esrc, xbf, w1p, w2p);

    aggx<<<3125, 256, 0, stream>>>(xbf, mbf, esrc, deg);

    gemm12<<<(NODES + 63) / 64, 256, 0, stream>>>(xbf, mbf, w1p, w2p, b1,
                                                  emb_out, V, NODES);

    agg2<<<(NODES * 8 + 255) / 256, 256, 0, stream>>>(V, esrc, deg, b2, logits_out);
}